// Round 4
// baseline (2418.730 us; speedup 1.0000x reference)
//
#include <hip/hip_runtime.h>
#include <math.h>

#define NN 100000
#define NE 400000
#define FI 64
#define HH 256
#define KT 50000

__device__ __forceinline__ float leaky02(float x){ return x >= 0.f ? x : 0.2f*x; }
__device__ __forceinline__ float preluf(float x, float a){ return x >= 0.f ? x : a*x; }

__device__ __forceinline__ float wredmax(float v){
  #pragma unroll
  for (int o=32;o>0;o>>=1) v = fmaxf(v, __shfl_xor(v, o, 64));
  return v;
}
__device__ __forceinline__ float wredsum(float v){
  #pragma unroll
  for (int o=32;o>0;o>>=1) v += __shfl_xor(v, o, 64);
  return v;
}
// reduce within each 32-lane half of the wave
__device__ __forceinline__ float hredsum(float v){
  #pragma unroll
  for (int o=16;o>0;o>>=1) v += __shfl_xor(v, o, 64);
  return v;
}

__device__ __forceinline__ void atomicMaxF(float* a, float v){
  if (v >= 0.f) atomicMax((int*)a, __float_as_int(v));
  else atomicMin((unsigned int*)a, __float_as_uint(v));
}

__device__ __forceinline__ void axpy4(float4& acc, float s, const float4 w){
  acc.x += s*w.x; acc.y += s*w.y; acc.z += s*w.z; acc.w += s*w.w;
}
__device__ __forceinline__ float4 bnprelu4(float4 v, float4 sc, float4 sh, float a){
  float4 r;
  r.x = preluf(v.x*sc.x+sh.x, a);
  r.y = preluf(v.y*sc.y+sh.y, a);
  r.z = preluf(v.z*sc.z+sh.z, a);
  r.w = preluf(v.w*sc.w+sh.w, a);
  return r;
}

// ---------------- CSR build ----------------
__global__ void k_count(const int* __restrict__ dst, int* __restrict__ deg){
  int e = blockIdx.x*blockDim.x + threadIdx.x;
  if (e < NE) atomicAdd(&deg[dst[e]], 1);
}

__global__ __launch_bounds__(1024) void k_scan1(const int* __restrict__ deg, int* __restrict__ rowptr, int* __restrict__ bsums){
  __shared__ int sm[1024];
  int t = threadIdx.x; int g = blockIdx.x*1024 + t;
  int v = (g < NN) ? deg[g] : 0;
  sm[t] = v; __syncthreads();
  for (int o=1;o<1024;o<<=1){
    int add = (t>=o)? sm[t-o] : 0;
    __syncthreads();
    sm[t] += add;
    __syncthreads();
  }
  if (g < NN) rowptr[g] = sm[t] - v;
  if (t == 1023) bsums[blockIdx.x] = sm[1023];
}

__global__ __launch_bounds__(128) void k_scan2(int* __restrict__ bsums, int nblk){
  __shared__ int sm[128];
  int t = threadIdx.x;
  int v = (t < nblk) ? bsums[t] : 0;
  sm[t] = v; __syncthreads();
  for (int o=1;o<128;o<<=1){
    int add = (t>=o)? sm[t-o] : 0;
    __syncthreads();
    sm[t] += add;
    __syncthreads();
  }
  if (t < nblk) bsums[t] = sm[t] - v;
}

__global__ __launch_bounds__(1024) void k_scan3(int* __restrict__ rowptr, const int* __restrict__ bsums, int* __restrict__ cursor){
  int g = blockIdx.x*1024 + threadIdx.x;
  if (g < NN){ int r = rowptr[g] + bsums[blockIdx.x]; rowptr[g] = r; cursor[g] = r; }
  if (blockIdx.x==0 && threadIdx.x==0) rowptr[NN] = NE;
}

__global__ void k_scatter(const int* __restrict__ src, const int* __restrict__ dst, int* __restrict__ cursor, int* __restrict__ adj){
  int e = blockIdx.x*blockDim.x + threadIdx.x;
  if (e < NE){ int d = dst[e]; int slot = atomicAdd(&cursor[d], 1); adj[slot] = src[e]; }
}

// ---------------- GEMM1: h = x(N,64) @ W(64,256); fused asrc/adst row dots ----------------
// 128x256 tile, thread = 16 rows x 8 cols (split halves); register-prefetch pipelined staging
__global__ __launch_bounds__(256, 2) void k_gemm1(const float* __restrict__ x, const float* __restrict__ W,
    const float* __restrict__ a_src, const float* __restrict__ a_dst,
    float* __restrict__ out, float* __restrict__ asrc, float* __restrict__ adst){
  __shared__ float Ws[32*HH];
  __shared__ float xs[128*32];
  int tid = threadIdx.x;
  int row0 = blockIdx.x * 128;
  int cg = tid & 31, rg = tid >> 5, c0 = cg*4;
  float4 acc[16][2];
  #pragma unroll
  for (int r=0;r<16;r++){ acc[r][0] = make_float4(0.f,0.f,0.f,0.f); acc[r][1] = make_float4(0.f,0.f,0.f,0.f); }
  float4 wreg[8]; float4 areg[4];
  auto stage = [&](int kc){
    #pragma unroll
    for (int j=0;j<8;j++){
      int i = tid + j*256;
      int kk = i>>6, c4 = i&63;
      wreg[j] = ((const float4*)(W + (size_t)(kc+kk)*HH))[c4];
    }
    #pragma unroll
    for (int j=0;j<4;j++){
      int i = tid + j*256;
      int r = i>>3, k4 = (i&7)*4;
      int grow = row0 + r; if (grow >= NN) grow = NN-1;
      areg[j] = *((const float4*)(x + (size_t)grow*FI + kc + k4));
    }
  };
  stage(0);
  for (int kc=0; kc<FI; kc+=32){
    __syncthreads();
    #pragma unroll
    for (int j=0;j<8;j++) ((float4*)Ws)[tid + j*256] = wreg[j];
    #pragma unroll
    for (int j=0;j<4;j++) ((float4*)xs)[tid + j*256] = areg[j];
    __syncthreads();
    if (kc + 32 < FI) stage(kc + 32);
    for (int kk=0; kk<32; kk+=4){
      float4 wv[4][2];
      #pragma unroll
      for (int j=0;j<4;j++){
        wv[j][0] = *((float4*)&Ws[(kk+j)*HH + c0]);
        wv[j][1] = *((float4*)&Ws[(kk+j)*HH + c0 + 128]);
      }
      #pragma unroll
      for (int r=0;r<16;r++){
        float4 av = *((float4*)&xs[(rg*16+r)*32 + kk]);
        axpy4(acc[r][0], av.x, wv[0][0]); axpy4(acc[r][1], av.x, wv[0][1]);
        axpy4(acc[r][0], av.y, wv[1][0]); axpy4(acc[r][1], av.y, wv[1][1]);
        axpy4(acc[r][0], av.z, wv[2][0]); axpy4(acc[r][1], av.z, wv[2][1]);
        axpy4(acc[r][0], av.w, wv[3][0]); axpy4(acc[r][1], av.w, wv[3][1]);
      }
    }
  }
  float4 as0 = *((const float4*)&a_src[c0]);
  float4 as1 = *((const float4*)&a_src[c0+128]);
  float4 ad0 = *((const float4*)&a_dst[c0]);
  float4 ad1 = *((const float4*)&a_dst[c0+128]);
  #pragma unroll
  for (int r=0;r<16;r++){
    int grow = row0 + rg*16 + r;
    float ps = acc[r][0].x*as0.x + acc[r][0].y*as0.y + acc[r][0].z*as0.z + acc[r][0].w*as0.w
             + acc[r][1].x*as1.x + acc[r][1].y*as1.y + acc[r][1].z*as1.z + acc[r][1].w*as1.w;
    float pd = acc[r][0].x*ad0.x + acc[r][0].y*ad0.y + acc[r][0].z*ad0.z + acc[r][0].w*ad0.w
             + acc[r][1].x*ad1.x + acc[r][1].y*ad1.y + acc[r][1].z*ad1.z + acc[r][1].w*ad1.w;
    ps = hredsum(ps); pd = hredsum(pd);
    if (grow < NN){
      *((float4*)&out[(size_t)grow*HH + c0]) = acc[r][0];
      *((float4*)&out[(size_t)grow*HH + c0 + 128]) = acc[r][1];
      if ((tid & 31) == 0){ asrc[grow] = ps; adst[grow] = pd; }
    }
  }
}

// ---------------- GAT: softmax over incoming edges (+self loop), max-aggregate alpha*h[src] ----------------
__global__ __launch_bounds__(256) void k_gat(const float* __restrict__ h, const float* __restrict__ asrc,
     const float* __restrict__ adst, const int* __restrict__ rowptr, const int* __restrict__ adj,
     const float* __restrict__ bias, float* __restrict__ out){
  int node = blockIdx.x*4 + (threadIdx.x>>6);
  int lane = threadIdx.x & 63;
  int rs = rowptr[node], re = rowptr[node+1];
  float adsti = adst[node];
  float eself = leaky02(asrc[node] + adsti);
  float m = eself;
  for (int j = rs + lane; j < re; j += 64) m = fmaxf(m, leaky02(asrc[adj[j]] + adsti));
  m = wredmax(m);
  float ssum = 0.f;
  for (int j = rs + lane; j < re; j += 64) ssum += expf(leaky02(asrc[adj[j]] + adsti) - m);
  ssum = wredsum(ssum) + expf(eself - m);
  float denom = ssum + 1e-16f;
  int c0 = lane*4;
  float aself = expf(eself - m)/denom;
  float4 hv = *((const float4*)&h[(size_t)node*HH + c0]);
  float4 acc = make_float4(hv.x*aself, hv.y*aself, hv.z*aself, hv.w*aself);
  for (int jb = rs; jb < re; jb += 64){
    int cnt = min(64, re - jb);
    int sv = 0; float av = 0.f;
    if (lane < cnt){ sv = adj[jb+lane]; av = expf(leaky02(asrc[sv] + adsti) - m)/denom; }
    for (int jj=0; jj<cnt; jj++){
      int sb = __shfl(sv, jj, 64);
      float ab = __shfl(av, jj, 64);
      float4 q = *((const float4*)&h[(size_t)sb*HH + c0]);
      acc.x = fmaxf(acc.x, q.x*ab); acc.y = fmaxf(acc.y, q.y*ab);
      acc.z = fmaxf(acc.z, q.z*ab); acc.w = fmaxf(acc.w, q.w*ab);
    }
  }
  float4 bv = *((const float4*)&bias[c0]);
  acc.x += bv.x; acc.y += bv.y; acc.z += bv.z; acc.w += bv.w;
  *((float4*)&out[(size_t)node*HH + c0]) = acc;
}

// ---------------- BatchNorm ----------------
__global__ __launch_bounds__(256) void k_bnstats(const float* __restrict__ x, float* __restrict__ sums, float* __restrict__ sumsq){
  int c = threadIdx.x;
  float s = 0.f, q = 0.f;
  for (int r = blockIdx.x; r < NN; r += gridDim.x){
    float v = x[(size_t)r*HH + c];
    s += v; q += v*v;
  }
  atomicAdd(&sums[c], s);
  atomicAdd(&sumsq[c], q);
}

__global__ __launch_bounds__(256) void k_bnfin(const float* __restrict__ sums, const float* __restrict__ sumsq,
    const float* __restrict__ g, const float* __restrict__ b, float* __restrict__ scale, float* __restrict__ shift){
  int c = threadIdx.x;
  float mean = sums[c]/(float)NN;
  float var = sumsq[c]/(float)NN - mean*mean;
  float rstd = rsqrtf(var + 1e-5f);
  float sc = g[c]*rstd;
  scale[c] = sc; shift[c] = b[c] - mean*sc;
}

// ---------------- apply BN+PReLU in place: x = prelu(x*scale+shift) ----------------
__global__ __launch_bounds__(256) void k_apply(float* __restrict__ x, const float* __restrict__ scale,
    const float* __restrict__ shift, const float* __restrict__ prelu){
  size_t i = (size_t)blockIdx.x*256 + threadIdx.x;   // float4 index over NN*64
  float slope = prelu[0];
  int c4 = (int)(i & 63), c0 = c4*4;
  float4 v = ((float4*)x)[i];
  float4 sc = *((const float4*)&scale[c0]);
  float4 sh = *((const float4*)&shift[c0]);
  ((float4*)x)[i] = bnprelu4(v, sc, sh, slope);
}

// ---------------- SAGE max-aggregate (x1 pre-activated) ----------------
__global__ __launch_bounds__(256) void k_sageagg(const float* __restrict__ x1, const int* __restrict__ rowptr,
    const int* __restrict__ adj, float* __restrict__ agg){
  int node = blockIdx.x*4 + (threadIdx.x>>6);
  int lane = threadIdx.x & 63;
  int rs = rowptr[node], re = rowptr[node+1];
  int c0 = lane*4;
  float4 acc = make_float4(-INFINITY,-INFINITY,-INFINITY,-INFINITY);
  for (int jb = rs; jb < re; jb += 64){
    int cnt = min(64, re - jb);
    int sv = (lane < cnt) ? adj[jb+lane] : 0;
    for (int jj=0; jj<cnt; jj++){
      int sb = __shfl(sv, jj, 64);
      float4 q = *((const float4*)&x1[(size_t)sb*HH + c0]);
      acc.x = fmaxf(acc.x, q.x); acc.y = fmaxf(acc.y, q.y);
      acc.z = fmaxf(acc.z, q.z); acc.w = fmaxf(acc.w, q.w);
    }
  }
  if (re == rs) acc = make_float4(0.f,0.f,0.f,0.f);
  *((float4*)&agg[(size_t)node*HH + c0]) = acc;
}

// ---------------- GEMM2: out = x1 @ Wr + agg @ Wl + bl  (K=512; in-place safe; pipelined) ----------------
// 128x256 tile, thread = 16 rows x 8 cols (split halves); fused BN2 stats
__global__ __launch_bounds__(256, 2) void k_gemm2(const float* __restrict__ x1, const float* __restrict__ agg,
    const float* __restrict__ Wr, const float* __restrict__ Wl,
    const float* __restrict__ bl, float* __restrict__ out,
    float* __restrict__ sums, float* __restrict__ sumsq){
  __shared__ float Ws[32*HH];
  __shared__ float xs[128*32];
  int tid = threadIdx.x;
  int row0 = blockIdx.x * 128;
  int cg = tid & 31, rg = tid >> 5, c0 = cg*4;
  float4 acc[16][2];
  #pragma unroll
  for (int r=0;r<16;r++){ acc[r][0] = make_float4(0.f,0.f,0.f,0.f); acc[r][1] = make_float4(0.f,0.f,0.f,0.f); }
  float4 wreg[8]; float4 areg[4];
  auto stage = [&](int kc){
    const float* wbase = (kc < HH) ? (Wr + (size_t)kc*HH) : (Wl + (size_t)(kc-HH)*HH);
    #pragma unroll
    for (int j=0;j<8;j++){
      int i = tid + j*256;
      int kk = i>>6, c4 = i&63;
      wreg[j] = ((const float4*)(wbase + (size_t)kk*HH))[c4];
    }
    const float* abase = (kc < HH) ? x1 : agg;
    int acol = (kc < HH) ? kc : kc - HH;
    #pragma unroll
    for (int j=0;j<4;j++){
      int i = tid + j*256;
      int r = i>>3, k4 = (i&7)*4;
      int grow = row0 + r; if (grow >= NN) grow = NN-1;
      areg[j] = *((const float4*)(abase + (size_t)grow*HH + acol + k4));
    }
  };
  stage(0);
  for (int kc=0; kc<2*HH; kc+=32){
    __syncthreads();
    #pragma unroll
    for (int j=0;j<8;j++) ((float4*)Ws)[tid + j*256] = wreg[j];
    #pragma unroll
    for (int j=0;j<4;j++) ((float4*)xs)[tid + j*256] = areg[j];
    __syncthreads();
    if (kc + 32 < 2*HH) stage(kc + 32);
    for (int kk=0; kk<32; kk+=4){
      float4 wv[4][2];
      #pragma unroll
      for (int j=0;j<4;j++){
        wv[j][0] = *((float4*)&Ws[(kk+j)*HH + c0]);
        wv[j][1] = *((float4*)&Ws[(kk+j)*HH + c0 + 128]);
      }
      #pragma unroll
      for (int r=0;r<16;r++){
        float4 av = *((float4*)&xs[(rg*16+r)*32 + kk]);
        axpy4(acc[r][0], av.x, wv[0][0]); axpy4(acc[r][1], av.x, wv[0][1]);
        axpy4(acc[r][0], av.y, wv[1][0]); axpy4(acc[r][1], av.y, wv[1][1]);
        axpy4(acc[r][0], av.z, wv[2][0]); axpy4(acc[r][1], av.z, wv[2][1]);
        axpy4(acc[r][0], av.w, wv[3][0]); axpy4(acc[r][1], av.w, wv[3][1]);
      }
    }
  }
  float4 b0 = *((const float4*)(bl + c0));
  float4 b1 = *((const float4*)(bl + c0 + 128));
  float s0=0,s1=0,s2=0,s3=0,s4=0,s5=0,s6=0,s7=0;
  float q0=0,q1=0,q2=0,q3=0,q4=0,q5=0,q6=0,q7=0;
  #pragma unroll
  for (int r=0;r<16;r++){
    int grow = row0 + rg*16 + r;
    if (grow < NN){
      acc[r][0].x += b0.x; acc[r][0].y += b0.y; acc[r][0].z += b0.z; acc[r][0].w += b0.w;
      acc[r][1].x += b1.x; acc[r][1].y += b1.y; acc[r][1].z += b1.z; acc[r][1].w += b1.w;
      *((float4*)&out[(size_t)grow*HH + c0]) = acc[r][0];
      *((float4*)&out[(size_t)grow*HH + c0 + 128]) = acc[r][1];
      s0 += acc[r][0].x; q0 += acc[r][0].x*acc[r][0].x;
      s1 += acc[r][0].y; q1 += acc[r][0].y*acc[r][0].y;
      s2 += acc[r][0].z; q2 += acc[r][0].z*acc[r][0].z;
      s3 += acc[r][0].w; q3 += acc[r][0].w*acc[r][0].w;
      s4 += acc[r][1].x; q4 += acc[r][1].x*acc[r][1].x;
      s5 += acc[r][1].y; q5 += acc[r][1].y*acc[r][1].y;
      s6 += acc[r][1].z; q6 += acc[r][1].z*acc[r][1].z;
      s7 += acc[r][1].w; q7 += acc[r][1].w*acc[r][1].w;
    }
  }
  // LDS reduce: xs reused as [8 rg][256 c] sums then sumsq (2048 floats each)
  __syncthreads();
  xs[rg*256 + c0+0] = s0; xs[rg*256 + c0+1] = s1; xs[rg*256 + c0+2] = s2; xs[rg*256 + c0+3] = s3;
  xs[rg*256 + c0+128+0] = s4; xs[rg*256 + c0+128+1] = s5; xs[rg*256 + c0+128+2] = s6; xs[rg*256 + c0+128+3] = s7;
  xs[2048 + rg*256 + c0+0] = q0; xs[2048 + rg*256 + c0+1] = q1; xs[2048 + rg*256 + c0+2] = q2; xs[2048 + rg*256 + c0+3] = q3;
  xs[2048 + rg*256 + c0+128+0] = q4; xs[2048 + rg*256 + c0+128+1] = q5; xs[2048 + rg*256 + c0+128+2] = q6; xs[2048 + rg*256 + c0+128+3] = q7;
  __syncthreads();
  {
    int c = tid;
    float ss = 0.f, qq = 0.f;
    #pragma unroll
    for (int g=0;g<8;g++){ ss += xs[g*256 + c]; qq += xs[2048 + g*256 + c]; }
    atomicAdd(&sums[c], ss);
    atomicAdd(&sumsq[c], qq);
  }
}

// ---------------- pool GEMVs: y2 = x2 @ Wrel, y2r = x2 @ Wroot ----------------
__global__ __launch_bounds__(256) void k_gemv2(const float* __restrict__ x2raw, const float* __restrict__ scale2,
    const float* __restrict__ shift2, const float* __restrict__ prelu2,
    const float* __restrict__ Wrel, const float* __restrict__ Wroot, float* __restrict__ y2, float* __restrict__ y2r){
  int node = blockIdx.x*4 + (threadIdx.x>>6);
  int lane = threadIdx.x & 63;
  int c0 = lane*4;
  float slope = prelu2[0];
  float4 v = *((const float4*)&x2raw[(size_t)node*HH + c0]);
  float4 sc = *((const float4*)&scale2[c0]);
  float4 sh = *((const float4*)&shift2[c0]);
  v = bnprelu4(v, sc, sh, slope);
  float4 wr = *((const float4*)&Wrel[c0]);
  float4 wo = *((const float4*)&Wroot[c0]);
  float pr = v.x*wr.x + v.y*wr.y + v.z*wr.z + v.w*wr.w;
  float po = v.x*wo.x + v.y*wo.y + v.z*wo.z + v.w*wo.w;
  pr = wredsum(pr); po = wredsum(po);
  if (lane==0){ y2[node] = pr; y2r[node] = po; }
}

__global__ void k_score(const int* __restrict__ rowptr, const int* __restrict__ adj, const float* __restrict__ y2,
    const float* __restrict__ y2r, const float* __restrict__ brel, float* __restrict__ score, unsigned* __restrict__ keys){
  int i = blockIdx.x*blockDim.x + threadIdx.x;
  if (i >= NN) return;
  float s = 0.f;
  int rs = rowptr[i], re = rowptr[i+1];
  for (int j=rs;j<re;j++) s += y2[adj[j]];
  float sc = s + brel[0] + y2r[i];
  score[i] = sc;
  unsigned u = __float_as_uint(sc);
  u = (u & 0x80000000u) ? ~u : (u | 0x80000000u);
  keys[i] = u;
}

// ---------------- top-K radix select (two 16-bit passes) ----------------
__global__ void k_hist1(const unsigned* __restrict__ keys, unsigned* __restrict__ hist){
  int i = blockIdx.x*blockDim.x + threadIdx.x;
  if (i < NN) atomicAdd(&hist[keys[i]>>16], 1u);
}

__global__ __launch_bounds__(256) void k_findbin1(const unsigned* __restrict__ hist, unsigned* __restrict__ scal){
  __shared__ unsigned csum[256];
  __shared__ unsigned above[256];
  int t = threadIdx.x;
  int base = t*256;
  unsigned s = 0;
  for (int b=0;b<256;b++) s += hist[base+b];
  csum[t] = s; __syncthreads();
  if (t==0){ unsigned run=0; for (int u=255;u>=0;u--){ above[u]=run; run += csum[u]; } }
  __syncthreads();
  unsigned ab = above[t];
  if (ab < (unsigned)KT && ab + csum[t] >= (unsigned)KT){
    unsigned run = ab;
    for (int b = base+255; b >= base; b--){
      unsigned hb = hist[b];
      if (run + hb >= (unsigned)KT){ scal[0] = (unsigned)b; scal[1] = run; break; }
      run += hb;
    }
  }
}

__global__ void k_hist2(const unsigned* __restrict__ keys, const unsigned* __restrict__ scal, unsigned* __restrict__ hist){
  int i = blockIdx.x*blockDim.x + threadIdx.x;
  if (i < NN){ unsigned k = keys[i]; if ((k>>16) == scal[0]) atomicAdd(&hist[k & 0xFFFFu], 1u); }
}

__global__ __launch_bounds__(256) void k_findbin2(const unsigned* __restrict__ hist, unsigned* __restrict__ scal){
  __shared__ unsigned csum[256];
  __shared__ unsigned above[256];
  int t = threadIdx.x;
  unsigned target = (unsigned)KT - scal[1];
  int base = t*256;
  unsigned s = 0;
  for (int b=0;b<256;b++) s += hist[base+b];
  csum[t] = s; __syncthreads();
  if (t==0){ unsigned run=0; for (int u=255;u>=0;u--){ above[u]=run; run += csum[u]; } }
  __syncthreads();
  unsigned ab = above[t];
  if (ab < target && ab + csum[t] >= target){
    unsigned run = ab;
    for (int b = base+255; b >= base; b--){
      unsigned hb = hist[b];
      if (run + hb >= target){
        scal[2] = (scal[0] << 16) | (unsigned)b;  // threshold key T
        scal[3] = target - run;                   // needed among ties
        scal[4] = hb;                             // tie count
        break;
      }
      run += hb;
    }
  }
}

__global__ void k_select(const unsigned* __restrict__ keys, const float* __restrict__ score,
    const unsigned* __restrict__ scal, int* __restrict__ sel, float* __restrict__ tval){
  int i = blockIdx.x*blockDim.x + threadIdx.x;
  if (i >= NN) return;
  unsigned T = scal[2], needed = scal[3], cnteq = scal[4];
  unsigned k = keys[i];
  int s = 0;
  if (k > T) s = 1;
  else if (k == T){
    if (cnteq <= needed) s = 1;
    else {
      unsigned rank = 0;
      for (int j=0;j<i;j++) rank += (keys[j] == T) ? 1u : 0u;   // rare tie path: stable (lowest-index) like lax.top_k
      s = (rank < needed) ? 1 : 0;
    }
  }
  sel[i] = s;
  tval[i] = s ? tanhf(score[i]) : 0.f;
}

__global__ __launch_bounds__(256) void k_embed(const float* __restrict__ x2raw, const float* __restrict__ scale2,
    const float* __restrict__ shift2, const float* __restrict__ prelu2, const int* __restrict__ sel,
    const float* __restrict__ tval, float* __restrict__ embed){
  int c = threadIdx.x;
  float slope = prelu2[0];
  float scv = scale2[c], shv = shift2[c];
  float best = -INFINITY;
  for (int r = blockIdx.x; r < NN; r += gridDim.x){
    if (sel[r]){
      float v = x2raw[(size_t)r*HH + c]*scv + shv;
      v = preluf(v, slope);
      best = fmaxf(best, v*tval[r]);
    }
  }
  atomicMaxF(&embed[c], best);
}

__global__ void k_initembed(float* __restrict__ embed){
  int i = threadIdx.x;
  if (i < 2*HH) embed[i] = -INFINITY;
}

// ---------------- head: z=[Ae,Ge,addf]; prelu(z@fc1+b); exp(h1@fc2+b) ----------------
__global__ __launch_bounds__(256) void k_head(const float* __restrict__ embed, const float* __restrict__ addf,
    const float* __restrict__ fc1W, const float* __restrict__ fc1b, const float* __restrict__ preluh,
    const float* __restrict__ fc2W, const float* __restrict__ fc2b, float* __restrict__ out){
  __shared__ float z[2*HH + 8];
  __shared__ float h1s[HH];
  __shared__ float red[4];
  int t = threadIdx.x;
  for (int i=t;i<2*HH;i+=256) z[i] = embed[i];
  if (t < 8) z[2*HH + t] = addf[t];
  __syncthreads();
  float acc = fc1b[t];
  for (int k=0;k<2*HH+8;k++) acc += z[k]*fc1W[(size_t)k*HH + t];
  float slope = preluh[0];
  h1s[t] = preluf(acc, slope);
  __syncthreads();
  float p = h1s[t]*fc2W[t];
  p = wredsum(p);
  if ((t & 63) == 0) red[t>>6] = p;
  __syncthreads();
  if (t == 0) out[0] = expf(red[0]+red[1]+red[2]+red[3] + fc2b[0]);
}

// ---------------- orchestration ----------------
extern "C" void kernel_launch(void* const* d_in, const int* in_sizes, int n_in,
                              void* d_out, int out_size, void* d_ws, size_t ws_size,
                              hipStream_t stream) {
  (void)in_sizes; (void)n_in; (void)out_size; (void)ws_size;
  char* ws = (char*)d_ws;
  size_t off = 0;
  auto alloc = [&](size_t bytes)->char*{
    char* p = ws + off;
    off = (off + bytes + 255) & ~(size_t)255;
    return p;
  };
  float* bufA   = (float*)alloc((size_t)NN*HH*4);   // h, later agg
  float* bufB   = (float*)alloc((size_t)NN*HH*4);   // gat out -> x1 (in place) -> sage out (in-place) -> x2 source
  float* asrc   = (float*)alloc((size_t)NN*4);
  float* adst   = (float*)alloc((size_t)NN*4);
  int*   rowptr = (int*)  alloc((size_t)(NN+1)*4);
  int*   adj    = (int*)  alloc((size_t)NE*4);
  int*   cursor = (int*)  alloc((size_t)NN*4);
  int*   bsums  = (int*)  alloc(128*4);
  float* sums   = (float*)alloc((size_t)2*HH*4);
  float* sumsq  = sums + HH;
  float* scale1 = (float*)alloc((size_t)HH*4);
  float* shift1 = (float*)alloc((size_t)HH*4);
  float* scale2 = (float*)alloc((size_t)HH*4);
  float* shift2 = (float*)alloc((size_t)HH*4);
  float* y2     = (float*)alloc((size_t)NN*4);
  float* y2r    = (float*)alloc((size_t)NN*4);
  float* score  = (float*)alloc((size_t)NN*4);
  unsigned* keys= (unsigned*)alloc((size_t)NN*4);
  int*   sel    = (int*)  alloc((size_t)NN*4);
  float* tval   = (float*)alloc((size_t)NN*4);
  unsigned* hist1 = (unsigned*)alloc(65536*4);
  unsigned* hist2 = (unsigned*)alloc(65536*4);
  unsigned* scal  = (unsigned*)alloc(64);
  float* embed  = (float*)alloc((size_t)2*HH*4);

  const float* addf = (const float*)d_in[2];

  k_initembed<<<dim3(1), dim3(512), 0, stream>>>(embed);

  for (int br = 0; br < 2; br++){
    const float* x  = (const float*)d_in[br==0 ? 0 : 1];
    const int*   ei = (const int*)  d_in[br==0 ? 3 : 4];
    const int* esrc = ei;
    const int* edst = ei + NE;
    int p = br==0 ? 5 : 21;
    const float* gat_W    = (const float*)d_in[p+0];
    const float* gat_asrc = (const float*)d_in[p+1];
    const float* gat_adst = (const float*)d_in[p+2];
    const float* gat_b    = (const float*)d_in[p+3];
    const float* bn1_g    = (const float*)d_in[p+4];
    const float* bn1_b    = (const float*)d_in[p+5];
    const float* prelu1   = (const float*)d_in[p+6];
    const float* sage_Wl  = (const float*)d_in[p+7];
    const float* sage_bl  = (const float*)d_in[p+8];
    const float* sage_Wr  = (const float*)d_in[p+9];
    const float* bn2_g    = (const float*)d_in[p+10];
    const float* bn2_b    = (const float*)d_in[p+11];
    const float* prelu2   = (const float*)d_in[p+12];
    const float* pool_Wrel= (const float*)d_in[p+13];
    const float* pool_brel= (const float*)d_in[p+14];
    const float* pool_Wroot=(const float*)d_in[p+15];

    // CSR by dst
    hipMemsetAsync(cursor, 0, (size_t)NN*4, stream);
    k_count<<<dim3((NE+255)/256), dim3(256), 0, stream>>>(edst, cursor);
    k_scan1<<<dim3(98), dim3(1024), 0, stream>>>(cursor, rowptr, bsums);
    k_scan2<<<dim3(1), dim3(128), 0, stream>>>(bsums, 98);
    k_scan3<<<dim3(98), dim3(1024), 0, stream>>>(rowptr, bsums, cursor);
    k_scatter<<<dim3((NE+255)/256), dim3(256), 0, stream>>>(esrc, edst, cursor, adj);

    // GAT (gemm1 fuses the asrc/adst row-dots)
    k_gemm1<<<dim3((NN+127)/128), dim3(256), 0, stream>>>(x, gat_W, gat_asrc, gat_adst, bufA, asrc, adst);
    k_gat<<<dim3(25000), dim3(256), 0, stream>>>(bufA, asrc, adst, rowptr, adj, gat_b, bufB);

    // BN1 stats + in-place apply -> x1 in bufB
    hipMemsetAsync(sums, 0, (size_t)2*HH*4, stream);
    k_bnstats<<<dim3(512), dim3(256), 0, stream>>>(bufB, sums, sumsq);
    k_bnfin<<<dim3(1), dim3(256), 0, stream>>>(sums, sumsq, bn1_g, bn1_b, scale1, shift1);
    k_apply<<<dim3(NN*64/256), dim3(256), 0, stream>>>(bufB, scale1, shift1, prelu1);

    // SAGE (agg into bufA; GEMM in-place into bufB, fused BN2 stats)
    k_sageagg<<<dim3(25000), dim3(256), 0, stream>>>(bufB, rowptr, adj, bufA);
    hipMemsetAsync(sums, 0, (size_t)2*HH*4, stream);
    k_gemm2<<<dim3((NN+127)/128), dim3(256), 0, stream>>>(bufB, bufA, sage_Wr, sage_Wl, sage_bl, bufB, sums, sumsq);
    k_bnfin<<<dim3(1), dim3(256), 0, stream>>>(sums, sumsq, bn2_g, bn2_b, scale2, shift2);

    // SAGPool
    k_gemv2<<<dim3(25000), dim3(256), 0, stream>>>(bufB, scale2, shift2, prelu2, pool_Wrel, pool_Wroot, y2, y2r);
    k_score<<<dim3((NN+255)/256), dim3(256), 0, stream>>>(rowptr, adj, y2, y2r, pool_brel, score, keys);
    hipMemsetAsync(hist1, 0, 65536*4, stream);
    hipMemsetAsync(hist2, 0, 65536*4, stream);
    k_hist1<<<dim3((NN+255)/256), dim3(256), 0, stream>>>(keys, hist1);
    k_findbin1<<<dim3(1), dim3(256), 0, stream>>>(hist1, scal);
    k_hist2<<<dim3((NN+255)/256), dim3(256), 0, stream>>>(keys, scal, hist2);
    k_findbin2<<<dim3(1), dim3(256), 0, stream>>>(hist2, scal);
    k_select<<<dim3((NN+255)/256), dim3(256), 0, stream>>>(keys, score, scal, sel, tval);
    k_embed<<<dim3(256), dim3(256), 0, stream>>>(bufB, scale2, shift2, prelu2, sel, tval, embed + br*HH);
  }

  k_head<<<dim3(1), dim3(256), 0, stream>>>(embed, addf,
      (const float*)d_in[37], (const float*)d_in[38], (const float*)d_in[39],
      (const float*)d_in[40], (const float*)d_in[41], (float*)d_out);
}

// Round 5
// 1771.963 us; speedup vs baseline: 1.3650x; 1.3650x over previous
//
#include <hip/hip_runtime.h>
#include <math.h>

#define NN 100000
#define NE 400000
#define FI 64
#define HH 256
#define KT 50000

typedef unsigned short u16;
typedef __attribute__((ext_vector_type(8))) short bf16x8;
typedef __attribute__((ext_vector_type(4))) float f32x4;

__device__ __forceinline__ float leaky02(float x){ return x >= 0.f ? x : 0.2f*x; }
__device__ __forceinline__ float preluf(float x, float a){ return x >= 0.f ? x : a*x; }

__device__ __forceinline__ float wredmax(float v){
  #pragma unroll
  for (int o=32;o>0;o>>=1) v = fmaxf(v, __shfl_xor(v, o, 64));
  return v;
}
__device__ __forceinline__ float wredsum(float v){
  #pragma unroll
  for (int o=32;o>0;o>>=1) v += __shfl_xor(v, o, 64);
  return v;
}
__device__ __forceinline__ float hredsum(float v){
  #pragma unroll
  for (int o=16;o>0;o>>=1) v += __shfl_xor(v, o, 64);
  return v;
}

__device__ __forceinline__ void atomicMaxF(float* a, float v){
  if (v >= 0.f) atomicMax((int*)a, __float_as_int(v));
  else atomicMin((unsigned int*)a, __float_as_uint(v));
}

__device__ __forceinline__ void axpy4(float4& acc, float s, const float4 w){
  acc.x += s*w.x; acc.y += s*w.y; acc.z += s*w.z; acc.w += s*w.w;
}
__device__ __forceinline__ float4 bnprelu4(float4 v, float4 sc, float4 sh, float a){
  float4 r;
  r.x = preluf(v.x*sc.x+sh.x, a);
  r.y = preluf(v.y*sc.y+sh.y, a);
  r.z = preluf(v.z*sc.z+sh.z, a);
  r.w = preluf(v.w*sc.w+sh.w, a);
  return r;
}

__device__ __forceinline__ u16 f2bf(float f){
  unsigned u = __float_as_uint(f);
  unsigned r = u + 0x7FFFu + ((u>>16)&1u);
  return (u16)(r>>16);
}
__device__ __forceinline__ float bf2f(u16 h){
  return __uint_as_float(((unsigned)h)<<16);
}

// ---------------- CSR build ----------------
__global__ void k_count(const int* __restrict__ dst, int* __restrict__ deg){
  int e = blockIdx.x*blockDim.x + threadIdx.x;
  if (e < NE) atomicAdd(&deg[dst[e]], 1);
}

__global__ __launch_bounds__(1024) void k_scan1(const int* __restrict__ deg, int* __restrict__ rowptr, int* __restrict__ bsums){
  __shared__ int sm[1024];
  int t = threadIdx.x; int g = blockIdx.x*1024 + t;
  int v = (g < NN) ? deg[g] : 0;
  sm[t] = v; __syncthreads();
  for (int o=1;o<1024;o<<=1){
    int add = (t>=o)? sm[t-o] : 0;
    __syncthreads();
    sm[t] += add;
    __syncthreads();
  }
  if (g < NN) rowptr[g] = sm[t] - v;
  if (t == 1023) bsums[blockIdx.x] = sm[1023];
}

__global__ __launch_bounds__(128) void k_scan2(int* __restrict__ bsums, int nblk){
  __shared__ int sm[128];
  int t = threadIdx.x;
  int v = (t < nblk) ? bsums[t] : 0;
  sm[t] = v; __syncthreads();
  for (int o=1;o<128;o<<=1){
    int add = (t>=o)? sm[t-o] : 0;
    __syncthreads();
    sm[t] += add;
    __syncthreads();
  }
  if (t < nblk) bsums[t] = sm[t] - v;
}

__global__ __launch_bounds__(1024) void k_scan3(int* __restrict__ rowptr, const int* __restrict__ bsums, int* __restrict__ cursor){
  int g = blockIdx.x*1024 + threadIdx.x;
  if (g < NN){ int r = rowptr[g] + bsums[blockIdx.x]; rowptr[g] = r; cursor[g] = r; }
  if (blockIdx.x==0 && threadIdx.x==0) rowptr[NN] = NE;
}

__global__ void k_scatter(const int* __restrict__ src, const int* __restrict__ dst, int* __restrict__ cursor, int* __restrict__ adj){
  int e = blockIdx.x*blockDim.x + threadIdx.x;
  if (e < NE){ int d = dst[e]; int slot = atomicAdd(&cursor[d], 1); adj[slot] = src[e]; }
}

// ---------------- GEMM1: h = x(N,64) @ W(64,256); fused asrc/adst row dots (r3 version) ----------------
__global__ __launch_bounds__(256, 2) void k_gemm1(const float* __restrict__ x, const float* __restrict__ W,
    const float* __restrict__ a_src, const float* __restrict__ a_dst,
    float* __restrict__ out, float* __restrict__ asrc, float* __restrict__ adst){
  __shared__ float Ws[32*HH];
  __shared__ float xs[128*32];
  int tid = threadIdx.x;
  int row0 = blockIdx.x * 128;
  int cg = tid & 31, rg = tid >> 5, c0 = cg*4;
  float4 acc[16][2];
  #pragma unroll
  for (int r=0;r<16;r++){ acc[r][0] = make_float4(0.f,0.f,0.f,0.f); acc[r][1] = make_float4(0.f,0.f,0.f,0.f); }
  for (int kc=0; kc<FI; kc+=32){
    __syncthreads();
    for (int i=tid;i<2048;i+=256){
      int kk = i>>6, c4 = i&63;
      ((float4*)Ws)[i] = ((const float4*)(W + (size_t)(kc+kk)*HH))[c4];
    }
    for (int i=tid;i<1024;i+=256){
      int r = i>>3, k4 = (i&7)*4;
      int grow = row0 + r; if (grow >= NN) grow = NN-1;
      ((float4*)xs)[i] = *((const float4*)(x + (size_t)grow*FI + kc + k4));
    }
    __syncthreads();
    for (int kk=0; kk<32; kk+=4){
      float4 wv[4][2];
      #pragma unroll
      for (int j=0;j<4;j++){
        wv[j][0] = *((float4*)&Ws[(kk+j)*HH + c0]);
        wv[j][1] = *((float4*)&Ws[(kk+j)*HH + c0 + 128]);
      }
      #pragma unroll
      for (int r=0;r<16;r++){
        float4 av = *((float4*)&xs[(rg*16+r)*32 + kk]);
        axpy4(acc[r][0], av.x, wv[0][0]); axpy4(acc[r][1], av.x, wv[0][1]);
        axpy4(acc[r][0], av.y, wv[1][0]); axpy4(acc[r][1], av.y, wv[1][1]);
        axpy4(acc[r][0], av.z, wv[2][0]); axpy4(acc[r][1], av.z, wv[2][1]);
        axpy4(acc[r][0], av.w, wv[3][0]); axpy4(acc[r][1], av.w, wv[3][1]);
      }
    }
  }
  float4 as0 = *((const float4*)&a_src[c0]);
  float4 as1 = *((const float4*)&a_src[c0+128]);
  float4 ad0 = *((const float4*)&a_dst[c0]);
  float4 ad1 = *((const float4*)&a_dst[c0+128]);
  #pragma unroll
  for (int r=0;r<16;r++){
    int grow = row0 + rg*16 + r;
    float ps = acc[r][0].x*as0.x + acc[r][0].y*as0.y + acc[r][0].z*as0.z + acc[r][0].w*as0.w
             + acc[r][1].x*as1.x + acc[r][1].y*as1.y + acc[r][1].z*as1.z + acc[r][1].w*as1.w;
    float pd = acc[r][0].x*ad0.x + acc[r][0].y*ad0.y + acc[r][0].z*ad0.z + acc[r][0].w*ad0.w
             + acc[r][1].x*ad1.x + acc[r][1].y*ad1.y + acc[r][1].z*ad1.z + acc[r][1].w*ad1.w;
    ps = hredsum(ps); pd = hredsum(pd);
    if (grow < NN){
      *((float4*)&out[(size_t)grow*HH + c0]) = acc[r][0];
      *((float4*)&out[(size_t)grow*HH + c0 + 128]) = acc[r][1];
      if ((tid & 31) == 0){ asrc[grow] = ps; adst[grow] = pd; }
    }
  }
}

// ---------------- GAT ----------------
__global__ __launch_bounds__(256) void k_gat(const float* __restrict__ h, const float* __restrict__ asrc,
     const float* __restrict__ adst, const int* __restrict__ rowptr, const int* __restrict__ adj,
     const float* __restrict__ bias, float* __restrict__ out){
  int node = blockIdx.x*4 + (threadIdx.x>>6);
  int lane = threadIdx.x & 63;
  int rs = rowptr[node], re = rowptr[node+1];
  float adsti = adst[node];
  float eself = leaky02(asrc[node] + adsti);
  float m = eself;
  for (int j = rs + lane; j < re; j += 64) m = fmaxf(m, leaky02(asrc[adj[j]] + adsti));
  m = wredmax(m);
  float ssum = 0.f;
  for (int j = rs + lane; j < re; j += 64) ssum += expf(leaky02(asrc[adj[j]] + adsti) - m);
  ssum = wredsum(ssum) + expf(eself - m);
  float denom = ssum + 1e-16f;
  int c0 = lane*4;
  float aself = expf(eself - m)/denom;
  float4 hv = *((const float4*)&h[(size_t)node*HH + c0]);
  float4 acc = make_float4(hv.x*aself, hv.y*aself, hv.z*aself, hv.w*aself);
  for (int jb = rs; jb < re; jb += 64){
    int cnt = min(64, re - jb);
    int sv = 0; float av = 0.f;
    if (lane < cnt){ sv = adj[jb+lane]; av = expf(leaky02(asrc[sv] + adsti) - m)/denom; }
    for (int jj=0; jj<cnt; jj++){
      int sb = __shfl(sv, jj, 64);
      float ab = __shfl(av, jj, 64);
      float4 q = *((const float4*)&h[(size_t)sb*HH + c0]);
      acc.x = fmaxf(acc.x, q.x*ab); acc.y = fmaxf(acc.y, q.y*ab);
      acc.z = fmaxf(acc.z, q.z*ab); acc.w = fmaxf(acc.w, q.w*ab);
    }
  }
  float4 bv = *((const float4*)&bias[c0]);
  acc.x += bv.x; acc.y += bv.y; acc.z += bv.z; acc.w += bv.w;
  *((float4*)&out[(size_t)node*HH + c0]) = acc;
}

// ---------------- BatchNorm ----------------
__global__ __launch_bounds__(256) void k_bnstats(const float* __restrict__ x, float* __restrict__ sums, float* __restrict__ sumsq){
  int c = threadIdx.x;
  float s = 0.f, q = 0.f;
  for (int r = blockIdx.x; r < NN; r += gridDim.x){
    float v = x[(size_t)r*HH + c];
    s += v; q += v*v;
  }
  atomicAdd(&sums[c], s);
  atomicAdd(&sumsq[c], q);
}

__global__ __launch_bounds__(256) void k_bnfin(const float* __restrict__ sums, const float* __restrict__ sumsq,
    const float* __restrict__ g, const float* __restrict__ b, float* __restrict__ scale, float* __restrict__ shift){
  int c = threadIdx.x;
  float mean = sums[c]/(float)NN;
  float var = sumsq[c]/(float)NN - mean*mean;
  float rstd = rsqrtf(var + 1e-5f);
  float sc = g[c]*rstd;
  scale[c] = sc; shift[c] = b[c] - mean*sc;
}

// ---------------- SAGE max-aggregate (bn1+prelu applied on the fly) ----------------
__global__ __launch_bounds__(256) void k_sageagg(const float* __restrict__ xin, const float* __restrict__ scale,
    const float* __restrict__ shift, const float* __restrict__ prelu, const int* __restrict__ rowptr,
    const int* __restrict__ adj, float* __restrict__ agg){
  int node = blockIdx.x*4 + (threadIdx.x>>6);
  int lane = threadIdx.x & 63;
  int rs = rowptr[node], re = rowptr[node+1];
  int c0 = lane*4;
  float slope = prelu[0];
  float4 sc = *((const float4*)&scale[c0]);
  float4 sh = *((const float4*)&shift[c0]);
  float4 acc = make_float4(-INFINITY,-INFINITY,-INFINITY,-INFINITY);
  for (int jb = rs; jb < re; jb += 64){
    int cnt = min(64, re - jb);
    int sv = (lane < cnt) ? adj[jb+lane] : 0;
    for (int jj=0; jj<cnt; jj++){
      int sb = __shfl(sv, jj, 64);
      float4 q = *((const float4*)&xin[(size_t)sb*HH + c0]);
      q = bnprelu4(q, sc, sh, slope);
      acc.x = fmaxf(acc.x, q.x); acc.y = fmaxf(acc.y, q.y);
      acc.z = fmaxf(acc.z, q.z); acc.w = fmaxf(acc.w, q.w);
    }
  }
  if (re == rs) acc = make_float4(0.f,0.f,0.f,0.f);
  *((float4*)&agg[(size_t)node*HH + c0]) = acc;
}

// ---------------- W pre-split: Wt[n][k] bf16 hi/lo, k = [Wr rows; Wl rows] ----------------
__global__ __launch_bounds__(256) void k_splitW(const float* __restrict__ Wr, const float* __restrict__ Wl,
    u16* __restrict__ WtHi, u16* __restrict__ WtLo){
  int idx = blockIdx.x*256 + threadIdx.x;    // 256*512
  int n = idx >> 9, k = idx & 511;
  float v = (k < HH) ? Wr[(size_t)k*HH + n] : Wl[(size_t)(k-HH)*HH + n];
  u16 hi = f2bf(v);
  float lo = v - bf2f(hi);
  WtHi[idx] = hi; WtLo[idx] = f2bf(lo);
}

// ---------------- GEMM2 (MFMA bf16x4 split): out = prelu(bn1(graw)) @ Wr + agg @ Wl + bl ----------------
// block = 64 rows x 256 cols, 4 waves, wave = 32x128 (2x8 tiles of 16x16), BK=32; fused BN2 stats.
// In-place safe: block reads only its own 64 rows, writes them in the epilogue.
__global__ __launch_bounds__(256, 2) void k_gemm2(const float* __restrict__ graw, const float* __restrict__ agg,
    const u16* __restrict__ WtHi, const u16* __restrict__ WtLo,
    const float* __restrict__ scale1, const float* __restrict__ shift1, const float* __restrict__ prelu1,
    const float* __restrict__ bl, float* __restrict__ out,
    float* __restrict__ sums, float* __restrict__ sumsq){
  __shared__ u16 As[2*64*32];    // [pl][m][k]
  __shared__ u16 Bs[2*256*32];   // [pl][n][k]
  int tid = threadIdx.x;
  int row0 = blockIdx.x*64;
  int wave = tid>>6, lane = tid&63;
  int l15 = lane&15, quad = lane>>4;
  int rowbase = (wave&1)*32, colbase = (wave>>1)*128;
  float slope = prelu1[0];
  f32x4 acc[2][8];
  #pragma unroll
  for (int mt=0;mt<2;mt++)
    #pragma unroll
    for (int nt=0;nt<8;nt++){ f32x4 z = {0.f,0.f,0.f,0.f}; acc[mt][nt] = z; }

  for (int kc=0; kc<2*HH; kc+=32){
    __syncthreads();
    // ---- stage A (64x32 fp32 -> split bf16 hi/lo) ----
    bool isx1 = (kc < HH);
    #pragma unroll
    for (int j=0;j<2;j++){
      int i = tid + j*256;           // 0..511 float4 tasks
      int m = i >> 3, kg = i & 7;    // m 0..63, 4 floats per task
      int grow = row0 + m; if (grow >= NN) grow = NN-1;
      int kcol = kc + kg*4;
      float4 v;
      if (isx1){
        v = *((const float4*)(graw + (size_t)grow*HH + kcol));
        float4 sc = *((const float4*)(scale1 + kcol));
        float4 sh = *((const float4*)(shift1 + kcol));
        v = bnprelu4(v, sc, sh, slope);
      } else {
        v = *((const float4*)(agg + (size_t)grow*HH + (kcol - HH)));
      }
      u16 h0=f2bf(v.x), h1=f2bf(v.y), h2=f2bf(v.z), h3=f2bf(v.w);
      u16 l0=f2bf(v.x-bf2f(h0)), l1=f2bf(v.y-bf2f(h1)), l2=f2bf(v.z-bf2f(h2)), l3=f2bf(v.w-bf2f(h3));
      unsigned long long ph = (unsigned long long)h0 | ((unsigned long long)h1<<16) | ((unsigned long long)h2<<32) | ((unsigned long long)h3<<48);
      unsigned long long pl = (unsigned long long)l0 | ((unsigned long long)l1<<16) | ((unsigned long long)l2<<32) | ((unsigned long long)l3<<48);
      *((unsigned long long*)&As[m*32 + kg*4])        = ph;
      *((unsigned long long*)&As[2048 + m*32 + kg*4]) = pl;
    }
    // ---- stage B (pre-split Wt: straight 16B copies) ----
    #pragma unroll
    for (int j=0;j<8;j++){
      int gi = tid + j*256;            // 0..2047 granules of 8 ushorts
      int pl = gi >> 10; int rem = gi & 1023;
      int n = rem >> 2; int kg = rem & 3;
      const u16* src = pl ? WtLo : WtHi;
      *((int4*)&Bs[pl*8192 + n*32 + kg*8]) = *((const int4*)&src[(size_t)n*512 + kc + kg*8]);
    }
    __syncthreads();
    // ---- fragments + MFMA ----
    bf16x8 af[2][2];
    #pragma unroll
    for (int mt=0;mt<2;mt++){
      int m = rowbase + mt*16 + l15;
      af[mt][0] = *((bf16x8*)&As[m*32 + quad*8]);
      af[mt][1] = *((bf16x8*)&As[2048 + m*32 + quad*8]);
    }
    for (int nt=0;nt<8;nt++){
      int n = colbase + nt*16 + l15;
      bf16x8 bh = *((bf16x8*)&Bs[n*32 + quad*8]);
      bf16x8 bo = *((bf16x8*)&Bs[8192 + n*32 + quad*8]);
      #pragma unroll
      for (int mt=0;mt<2;mt++){
        acc[mt][nt] = __builtin_amdgcn_mfma_f32_16x16x32_bf16(af[mt][0], bh, acc[mt][nt], 0, 0, 0);
        acc[mt][nt] = __builtin_amdgcn_mfma_f32_16x16x32_bf16(af[mt][0], bo, acc[mt][nt], 0, 0, 0);
        acc[mt][nt] = __builtin_amdgcn_mfma_f32_16x16x32_bf16(af[mt][1], bh, acc[mt][nt], 0, 0, 0);
        acc[mt][nt] = __builtin_amdgcn_mfma_f32_16x16x32_bf16(af[mt][1], bo, acc[mt][nt], 0, 0, 0);
      }
    }
  }
  // ---- epilogue: bias, store, BN2 partial stats ----
  float psum[8], psq[8];
  #pragma unroll
  for (int nt=0;nt<8;nt++){
    int c = colbase + nt*16 + l15;
    float bcol = bl[c];
    float s=0.f, q=0.f;
    #pragma unroll
    for (int mt=0;mt<2;mt++){
      int gbase = row0 + rowbase + mt*16 + quad*4;
      #pragma unroll
      for (int r=0;r<4;r++){
        int grow = gbase + r;
        float v = acc[mt][nt][r] + bcol;
        if (grow < NN){
          out[(size_t)grow*HH + c] = v;
          s += v; q += v*v;
        }
      }
    }
    psum[nt]=s; psq[nt]=q;
  }
  __syncthreads();
  float* sm = (float*)As;        // reuse: 512 floats
  sm[tid] = 0.f; sm[tid+256] = 0.f;
  __syncthreads();
  #pragma unroll
  for (int nt=0;nt<8;nt++){
    int c = colbase + nt*16 + l15;
    atomicAdd(&sm[c], psum[nt]);
    atomicAdd(&sm[256+c], psq[nt]);
  }
  __syncthreads();
  atomicAdd(&sums[tid], sm[tid]);
  atomicAdd(&sumsq[tid], sm[256+tid]);
}

// ---------------- pool GEMVs ----------------
__global__ __launch_bounds__(256) void k_gemv2(const float* __restrict__ x2raw, const float* __restrict__ scale2,
    const float* __restrict__ shift2, const float* __restrict__ prelu2,
    const float* __restrict__ Wrel, const float* __restrict__ Wroot, float* __restrict__ y2, float* __restrict__ y2r){
  int node = blockIdx.x*4 + (threadIdx.x>>6);
  int lane = threadIdx.x & 63;
  int c0 = lane*4;
  float slope = prelu2[0];
  float4 v = *((const float4*)&x2raw[(size_t)node*HH + c0]);
  float4 sc = *((const float4*)&scale2[c0]);
  float4 sh = *((const float4*)&shift2[c0]);
  v = bnprelu4(v, sc, sh, slope);
  float4 wr = *((const float4*)&Wrel[c0]);
  float4 wo = *((const float4*)&Wroot[c0]);
  float pr = v.x*wr.x + v.y*wr.y + v.z*wr.z + v.w*wr.w;
  float po = v.x*wo.x + v.y*wo.y + v.z*wo.z + v.w*wo.w;
  pr = wredsum(pr); po = wredsum(po);
  if (lane==0){ y2[node] = pr; y2r[node] = po; }
}

__global__ void k_score(const int* __restrict__ rowptr, const int* __restrict__ adj, const float* __restrict__ y2,
    const float* __restrict__ y2r, const float* __restrict__ brel, float* __restrict__ score, unsigned* __restrict__ keys){
  int i = blockIdx.x*blockDim.x + threadIdx.x;
  if (i >= NN) return;
  float s = 0.f;
  int rs = rowptr[i], re = rowptr[i+1];
  for (int j=rs;j<re;j++) s += y2[adj[j]];
  float sc = s + brel[0] + y2r[i];
  score[i] = sc;
  unsigned u = __float_as_uint(sc);
  u = (u & 0x80000000u) ? ~u : (u | 0x80000000u);
  keys[i] = u;
}

// ---------------- top-K radix select ----------------
__global__ void k_hist1(const unsigned* __restrict__ keys, unsigned* __restrict__ hist){
  int i = blockIdx.x*blockDim.x + threadIdx.x;
  if (i < NN) atomicAdd(&hist[keys[i]>>16], 1u);
}

__global__ __launch_bounds__(256) void k_findbin1(const unsigned* __restrict__ hist, unsigned* __restrict__ scal){
  __shared__ unsigned csum[256];
  __shared__ unsigned above[256];
  int t = threadIdx.x;
  int base = t*256;
  unsigned s = 0;
  for (int b=0;b<256;b++) s += hist[base+b];
  csum[t] = s; __syncthreads();
  if (t==0){ unsigned run=0; for (int u=255;u>=0;u--){ above[u]=run; run += csum[u]; } }
  __syncthreads();
  unsigned ab = above[t];
  if (ab < (unsigned)KT && ab + csum[t] >= (unsigned)KT){
    unsigned run = ab;
    for (int b = base+255; b >= base; b--){
      unsigned hb = hist[b];
      if (run + hb >= (unsigned)KT){ scal[0] = (unsigned)b; scal[1] = run; break; }
      run += hb;
    }
  }
}

__global__ void k_hist2(const unsigned* __restrict__ keys, const unsigned* __restrict__ scal, unsigned* __restrict__ hist){
  int i = blockIdx.x*blockDim.x + threadIdx.x;
  if (i < NN){ unsigned k = keys[i]; if ((k>>16) == scal[0]) atomicAdd(&hist[k & 0xFFFFu], 1u); }
}

__global__ __launch_bounds__(256) void k_findbin2(const unsigned* __restrict__ hist, unsigned* __restrict__ scal){
  __shared__ unsigned csum[256];
  __shared__ unsigned above[256];
  int t = threadIdx.x;
  unsigned target = (unsigned)KT - scal[1];
  int base = t*256;
  unsigned s = 0;
  for (int b=0;b<256;b++) s += hist[base+b];
  csum[t] = s; __syncthreads();
  if (t==0){ unsigned run=0; for (int u=255;u>=0;u--){ above[u]=run; run += csum[u]; } }
  __syncthreads();
  unsigned ab = above[t];
  if (ab < target && ab + csum[t] >= target){
    unsigned run = ab;
    for (int b = base+255; b >= base; b--){
      unsigned hb = hist[b];
      if (run + hb >= target){
        scal[2] = (scal[0] << 16) | (unsigned)b;
        scal[3] = target - run;
        scal[4] = hb;
        break;
      }
      run += hb;
    }
  }
}

__global__ void k_select(const unsigned* __restrict__ keys, const float* __restrict__ score,
    const unsigned* __restrict__ scal, int* __restrict__ sel, float* __restrict__ tval){
  int i = blockIdx.x*blockDim.x + threadIdx.x;
  if (i >= NN) return;
  unsigned T = scal[2], needed = scal[3], cnteq = scal[4];
  unsigned k = keys[i];
  int s = 0;
  if (k > T) s = 1;
  else if (k == T){
    if (cnteq <= needed) s = 1;
    else {
      unsigned rank = 0;
      for (int j=0;j<i;j++) rank += (keys[j] == T) ? 1u : 0u;
      s = (rank < needed) ? 1 : 0;
    }
  }
  sel[i] = s;
  tval[i] = s ? tanhf(score[i]) : 0.f;
}

__global__ __launch_bounds__(256) void k_embed(const float* __restrict__ x2raw, const float* __restrict__ scale2,
    const float* __restrict__ shift2, const float* __restrict__ prelu2, const int* __restrict__ sel,
    const float* __restrict__ tval, float* __restrict__ embed){
  int c = threadIdx.x;
  float slope = prelu2[0];
  float scv = scale2[c], shv = shift2[c];
  float best = -INFINITY;
  for (int r = blockIdx.x; r < NN; r += gridDim.x){
    if (sel[r]){
      float v = x2raw[(size_t)r*HH + c]*scv + shv;
      v = preluf(v, slope);
      best = fmaxf(best, v*tval[r]);
    }
  }
  atomicMaxF(&embed[c], best);
}

__global__ void k_initembed(float* __restrict__ embed){
  int i = threadIdx.x;
  if (i < 2*HH) embed[i] = -INFINITY;
}

// ---------------- head ----------------
__global__ __launch_bounds__(256) void k_head(const float* __restrict__ embed, const float* __restrict__ addf,
    const float* __restrict__ fc1W, const float* __restrict__ fc1b, const float* __restrict__ preluh,
    const float* __restrict__ fc2W, const float* __restrict__ fc2b, float* __restrict__ out){
  __shared__ float z[2*HH + 8];
  __shared__ float h1s[HH];
  __shared__ float red[4];
  int t = threadIdx.x;
  for (int i=t;i<2*HH;i+=256) z[i] = embed[i];
  if (t < 8) z[2*HH + t] = addf[t];
  __syncthreads();
  float acc = fc1b[t];
  for (int k=0;k<2*HH+8;k++) acc += z[k]*fc1W[(size_t)k*HH + t];
  float slope = preluh[0];
  h1s[t] = preluf(acc, slope);
  __syncthreads();
  float p = h1s[t]*fc2W[t];
  p = wredsum(p);
  if ((t & 63) == 0) red[t>>6] = p;
  __syncthreads();
  if (t == 0) out[0] = expf(red[0]+red[1]+red[2]+red[3] + fc2b[0]);
}

// ---------------- orchestration ----------------
extern "C" void kernel_launch(void* const* d_in, const int* in_sizes, int n_in,
                              void* d_out, int out_size, void* d_ws, size_t ws_size,
                              hipStream_t stream) {
  (void)in_sizes; (void)n_in; (void)out_size; (void)ws_size;
  char* ws = (char*)d_ws;
  size_t off = 0;
  auto alloc = [&](size_t bytes)->char*{
    char* p = ws + off;
    off = (off + bytes + 255) & ~(size_t)255;
    return p;
  };
  float* bufA   = (float*)alloc((size_t)NN*HH*4);   // h, later agg
  float* bufB   = (float*)alloc((size_t)NN*HH*4);   // gat out -> sage out (in-place) -> x2 source
  float* asrc   = (float*)alloc((size_t)NN*4);
  float* adst   = (float*)alloc((size_t)NN*4);
  int*   rowptr = (int*)  alloc((size_t)(NN+1)*4);
  int*   adj    = (int*)  alloc((size_t)NE*4);
  int*   cursor = (int*)  alloc((size_t)NN*4);
  int*   bsums  = (int*)  alloc(128*4);
  float* sums   = (float*)alloc((size_t)2*HH*4);
  float* sumsq  = sums + HH;
  float* scale1 = (float*)alloc((size_t)HH*4);
  float* shift1 = (float*)alloc((size_t)HH*4);
  float* scale2 = (float*)alloc((size_t)HH*4);
  float* shift2 = (float*)alloc((size_t)HH*4);
  float* y2     = (float*)alloc((size_t)NN*4);
  float* y2r    = (float*)alloc((size_t)NN*4);
  float* score  = (float*)alloc((size_t)NN*4);
  unsigned* keys= (unsigned*)alloc((size_t)NN*4);
  int*   sel    = (int*)  alloc((size_t)NN*4);
  float* tval   = (float*)alloc((size_t)NN*4);
  unsigned* hist1 = (unsigned*)alloc(65536*4);
  unsigned* hist2 = (unsigned*)alloc(65536*4);
  unsigned* scal  = (unsigned*)alloc(64);
  float* embed  = (float*)alloc((size_t)2*HH*4);
  u16* WtHi   = (u16*)alloc((size_t)HH*512*2);
  u16* WtLo   = (u16*)alloc((size_t)HH*512*2);

  const float* addf = (const float*)d_in[2];

  k_initembed<<<dim3(1), dim3(512), 0, stream>>>(embed);

  for (int br = 0; br < 2; br++){
    const float* x  = (const float*)d_in[br==0 ? 0 : 1];
    const int*   ei = (const int*)  d_in[br==0 ? 3 : 4];
    const int* esrc = ei;
    const int* edst = ei + NE;
    int p = br==0 ? 5 : 21;
    const float* gat_W    = (const float*)d_in[p+0];
    const float* gat_asrc = (const float*)d_in[p+1];
    const float* gat_adst = (const float*)d_in[p+2];
    const float* gat_b    = (const float*)d_in[p+3];
    const float* bn1_g    = (const float*)d_in[p+4];
    const float* bn1_b    = (const float*)d_in[p+5];
    const float* prelu1   = (const float*)d_in[p+6];
    const float* sage_Wl  = (const float*)d_in[p+7];
    const float* sage_bl  = (const float*)d_in[p+8];
    const float* sage_Wr  = (const float*)d_in[p+9];
    const float* bn2_g    = (const float*)d_in[p+10];
    const float* bn2_b    = (const float*)d_in[p+11];
    const float* prelu2   = (const float*)d_in[p+12];
    const float* pool_Wrel= (const float*)d_in[p+13];
    const float* pool_brel= (const float*)d_in[p+14];
    const float* pool_Wroot=(const float*)d_in[p+15];

    // CSR by dst
    hipMemsetAsync(cursor, 0, (size_t)NN*4, stream);
    k_count<<<dim3((NE+255)/256), dim3(256), 0, stream>>>(edst, cursor);
    k_scan1<<<dim3(98), dim3(1024), 0, stream>>>(cursor, rowptr, bsums);
    k_scan2<<<dim3(1), dim3(128), 0, stream>>>(bsums, 98);
    k_scan3<<<dim3(98), dim3(1024), 0, stream>>>(rowptr, bsums, cursor);
    k_scatter<<<dim3((NE+255)/256), dim3(256), 0, stream>>>(esrc, edst, cursor, adj);

    // W pre-split for the MFMA gemm2
    k_splitW<<<dim3(512), dim3(256), 0, stream>>>(sage_Wr, sage_Wl, WtHi, WtLo);

    // GAT (gemm1 fuses the asrc/adst row-dots)
    k_gemm1<<<dim3((NN+127)/128), dim3(256), 0, stream>>>(x, gat_W, gat_asrc, gat_adst, bufA, asrc, adst);
    k_gat<<<dim3(25000), dim3(256), 0, stream>>>(bufA, asrc, adst, rowptr, adj, gat_b, bufB);

    // BN1
    hipMemsetAsync(sums, 0, (size_t)2*HH*4, stream);
    k_bnstats<<<dim3(512), dim3(256), 0, stream>>>(bufB, sums, sumsq);
    k_bnfin<<<dim3(1), dim3(256), 0, stream>>>(sums, sumsq, bn1_g, bn1_b, scale1, shift1);

    // SAGE (agg into bufA; MFMA GEMM in-place into bufB with fused BN2 stats)
    k_sageagg<<<dim3(25000), dim3(256), 0, stream>>>(bufB, scale1, shift1, prelu1, rowptr, adj, bufA);
    hipMemsetAsync(sums, 0, (size_t)2*HH*4, stream);
    k_gemm2<<<dim3((NN+63)/64), dim3(256), 0, stream>>>(bufB, bufA, WtHi, WtLo,
        scale1, shift1, prelu1, sage_bl, bufB, sums, sumsq);
    k_bnfin<<<dim3(1), dim3(256), 0, stream>>>(sums, sumsq, bn2_g, bn2_b, scale2, shift2);

    // SAGPool
    k_gemv2<<<dim3(25000), dim3(256), 0, stream>>>(bufB, scale2, shift2, prelu2, pool_Wrel, pool_Wroot, y2, y2r);
    k_score<<<dim3((NN+255)/256), dim3(256), 0, stream>>>(rowptr, adj, y2, y2r, pool_brel, score, keys);
    hipMemsetAsync(hist1, 0, 65536*4, stream);
    hipMemsetAsync(hist2, 0, 65536*4, stream);
    k_hist1<<<dim3((NN+255)/256), dim3(256), 0, stream>>>(keys, hist1);
    k_findbin1<<<dim3(1), dim3(256), 0, stream>>>(hist1, scal);
    k_hist2<<<dim3((NN+255)/256), dim3(256), 0, stream>>>(keys, scal, hist2);
    k_findbin2<<<dim3(1), dim3(256), 0, stream>>>(hist2, scal);
    k_select<<<dim3((NN+255)/256), dim3(256), 0, stream>>>(keys, score, scal, sel, tval);
    k_embed<<<dim3(256), dim3(256), 0, stream>>>(bufB, scale2, shift2, prelu2, sel, tval, embed + br*HH);
  }

  k_head<<<dim3(1), dim3(256), 0, stream>>>(embed, addf,
      (const float*)d_in[37], (const float*)d_in[38], (const float*)d_in[39],
      (const float*)d_in[40], (const float*)d_in[41], (float*)d_out);
}